// Round 16
// baseline (80.071 us; speedup 1.0000x reference)
//
#include <hip/hip_runtime.h>
#include <hip/hip_fp16.h>

#define N_NODES 100000
#define DIM 16
#define BSHIFT 6
#define BNODES 64                                   // nodes per bucket
#define NB ((N_NODES + BNODES - 1) / BNODES)        // 1563 buckets
#define TB 512
#define CHUNK 8192                                  // edges per place/hist wg
#define CAPB 2432                                   // sort_gather LDS tile size
#define QSCALE 32767.0f

// ---------------- two-level bucket sort + fused node-sort/gather ----------------

// A (+X): convert x->fp16 (grid-stride), then per-workgroup histogram of
// dst-buckets. Vectorized int4 dst reads.
__global__ __launch_bounds__(TB) void hist_kernel(const float* __restrict__ x,
                                                  __half* __restrict__ xh,
                                                  int n8,
                                                  const int* __restrict__ dst,
                                                  unsigned* __restrict__ H,
                                                  int E) {
    // convert: 8 floats -> 16B per thread
    int gid = blockIdx.x * TB + threadIdx.x;
    int gsz = gridDim.x * TB;
    for (int i = gid; i < n8; i += gsz) {
        float4 a = ((const float4*)x)[2 * i];
        float4 b = ((const float4*)x)[2 * i + 1];
        __half2 h0 = __floats2half2_rn(a.x, a.y);
        __half2 h1 = __floats2half2_rn(a.z, a.w);
        __half2 h2 = __floats2half2_rn(b.x, b.y);
        __half2 h3 = __floats2half2_rn(b.z, b.w);
        uint4 u;
        u.x = *reinterpret_cast<unsigned*>(&h0);
        u.y = *reinterpret_cast<unsigned*>(&h1);
        u.z = *reinterpret_cast<unsigned*>(&h2);
        u.w = *reinterpret_cast<unsigned*>(&h3);
        ((uint4*)xh)[i] = u;
    }

    __shared__ unsigned hist[NB];
    int tid = threadIdx.x;
    for (int i = tid; i < NB; i += TB) hist[i] = 0;
    __syncthreads();
    int e0 = blockIdx.x * CHUNK;
    int e1 = min(e0 + CHUNK, E);
    int nquad = ((E & 3) == 0) ? ((e1 - e0) >> 2) : 0;
    for (int qi = tid; qi < nquad; qi += TB) {
        int4 d4 = *(const int4*)(dst + e0 + qi * 4);
        atomicAdd(&hist[((unsigned)d4.x) >> BSHIFT], 1u);
        atomicAdd(&hist[((unsigned)d4.y) >> BSHIFT], 1u);
        atomicAdd(&hist[((unsigned)d4.z) >> BSHIFT], 1u);
        atomicAdd(&hist[((unsigned)d4.w) >> BSHIFT], 1u);
    }
    for (int e = e0 + nquad * 4 + tid; e < e1; e += TB)
        atomicAdd(&hist[((unsigned)dst[e]) >> BSHIFT], 1u);
    __syncthreads();
    unsigned* row = H + (size_t)blockIdx.x * NB;
    for (int i = tid; i < NB; i += TB) row[i] = hist[i];
}

// Block-wide exclusive scan (nthreads threads, multiple of 64, <=1024).
__device__ inline unsigned block_scan_excl(unsigned v, int tid, int nthreads,
                                           unsigned* warp_lds, unsigned* total_out) {
    unsigned x = v;
#pragma unroll
    for (int off = 1; off < 64; off <<= 1) {
        unsigned y = __shfl_up(x, off);
        if ((tid & 63) >= off) x += y;
    }
    int wid = tid >> 6;
    int nw = nthreads >> 6;
    if ((tid & 63) == 63) warp_lds[wid] = x;
    __syncthreads();
    if (tid < nw) {
        unsigned w = warp_lds[tid];
#pragma unroll
        for (int off = 1; off < 16; off <<= 1) {
            unsigned y = __shfl_up(w, off);
            if (tid >= off) w += y;
        }
        warp_lds[tid] = w;   // inclusive per-wave totals
    }
    __syncthreads();
    unsigned wbase = (wid > 0) ? warp_lds[wid - 1] : 0u;
    unsigned incl = x + wbase;
    if (total_out && tid == nthreads - 1) *total_out = incl;
    return incl - v;
}

// B1: for each bucket b, exclusive scan of H[wg][b] over wgs (in place) + total.
__global__ __launch_bounds__(TB) void scan_wg_kernel(unsigned* __restrict__ H,
                                                     unsigned* __restrict__ totals,
                                                     int nwg) {
    __shared__ unsigned warp_lds[16];
    int b = blockIdx.x;
    int tid = threadIdx.x;
    unsigned v = (tid < nwg) ? H[(size_t)tid * NB + b] : 0u;
    unsigned excl = block_scan_excl(v, tid, TB, warp_lds, &totals[b]);
    if (tid < nwg) H[(size_t)tid * NB + b] = excl;
}

// B2: exclusive scan of bucket totals -> bucket base offsets (2 bins/thread).
__global__ __launch_bounds__(1024) void scan_bucket_kernel(const unsigned* __restrict__ totals,
                                                           unsigned* __restrict__ base) {
    __shared__ unsigned warp_lds[16];
    int tid = threadIdx.x;
    int b0 = 2 * tid, b1 = 2 * tid + 1;
    unsigned v0 = (b0 < NB) ? totals[b0] : 0u;
    unsigned v1 = (b1 < NB) ? totals[b1] : 0u;
    unsigned excl = block_scan_excl(v0 + v1, tid, 1024, warp_lds, nullptr);
    if (b0 < NB) base[b0] = excl;
    if (b1 < NB) base[b1] = excl + v0;
}

// C: LDS counting sort of the wg's chunk into (u8 dloc key, u32 src<<15|q15
// payload). Chunk counts from diffing adjacent scanned H rows. Vectorized
// 4-edge loads. Bin scan: 4 bins/thread. Writeout: 8 lanes/bucket, 8/wave.
__global__ __launch_bounds__(TB) void place_kernel(const int* __restrict__ src,
                                                   const int* __restrict__ dst,
                                                   const float* __restrict__ probs,
                                                   const unsigned* __restrict__ O,
                                                   const unsigned* __restrict__ totals,
                                                   const unsigned* __restrict__ base,
                                                   unsigned char* __restrict__ key,
                                                   unsigned* __restrict__ payload,
                                                   int E, int nwg) {
    __shared__ unsigned recs_pl[CHUNK];           // 32 KB
    __shared__ unsigned char recs_k[CHUNK];       // 8 KB
    __shared__ unsigned lstart[NB];               // 6.25 KB each
    __shared__ unsigned lcur[NB];
    __shared__ unsigned gdst[NB];
    __shared__ unsigned warp_lds[16];
    int tid = threadIdx.x;
    int wg = blockIdx.x;
    int e0 = wg * CHUNK;
    int e1 = min(e0 + CHUNK, E);
    bool last = (wg == nwg - 1);

    const unsigned* row  = O + (size_t)wg * NB;
    const unsigned* rown = O + (size_t)(wg + 1) * NB;
    for (int i = tid; i < NB; i += TB) {
        unsigned h = row[i];
        unsigned hn = last ? totals[i] : rown[i];
        gdst[i] = base[i] + h;
        lcur[i] = hn - h;                  // count for this wg
    }
    __syncthreads();

    // scan NB bins, 4 per thread (4*TB = 2048 >= NB)
    int bb0 = 4 * tid;
    unsigned c[4];
    unsigned csum = 0;
#pragma unroll
    for (int u = 0; u < 4; ++u) {
        c[u] = (bb0 + u < NB) ? lcur[bb0 + u] : 0u;
        csum += c[u];
    }
    unsigned excl = block_scan_excl(csum, tid, TB, warp_lds, nullptr);
    __syncthreads();
    unsigned run = excl;
#pragma unroll
    for (int u = 0; u < 4; ++u) {
        if (bb0 + u < NB) { lstart[bb0 + u] = run; lcur[bb0 + u] = run; }
        run += c[u];
    }
    __syncthreads();

    // place records into LDS, bucket-sorted (vectorized 4-edge loads)
    int nquad = ((E & 3) == 0) ? ((e1 - e0) >> 2) : 0;
    for (int qi = tid; qi < nquad; qi += TB) {
        int e = e0 + qi * 4;
        int4   s4 = *(const int4*)(src + e);
        int4   d4 = *(const int4*)(dst + e);
        float4 p4 = *(const float4*)(probs + e);
#pragma unroll
        for (int u = 0; u < 4; ++u) {
            unsigned d = (unsigned)((&d4.x)[u]);
            unsigned s = (unsigned)((&s4.x)[u]);
            float p = (&p4.x)[u];
            unsigned bb = d >> BSHIFT;
            unsigned pos = atomicAdd(&lcur[bb], 1u);
            unsigned q = __float2uint_rn(p * QSCALE);
            recs_pl[pos] = (s << 15) | q;                 // src 17b | q 15b
            recs_k[pos] = (unsigned char)(d & (BNODES - 1));
        }
    }
    for (int e = e0 + nquad * 4 + tid; e < e1; e += TB) {
        unsigned d = (unsigned)dst[e];
        unsigned s = (unsigned)src[e];
        float p = probs[e];
        unsigned bb = d >> BSHIFT;
        unsigned pos = atomicAdd(&lcur[bb], 1u);
        unsigned q = __float2uint_rn(p * QSCALE);
        recs_pl[pos] = (s << 15) | q;
        recs_k[pos] = (unsigned char)(d & (BNODES - 1));
    }
    __syncthreads();

    // writeout: 8 lanes per bucket, 8 buckets per wave (runs avg ~5 recs)
    int wv = tid >> 6, ln = tid & 63;
    int bq = ln >> 3, ln8 = ln & 7;
    for (int bb = wv * 8; bb < NB; bb += (TB >> 6) * 8) {
        int b = bb + bq;
        unsigned st = 0, cnt = 0, g = 0;
        if (b < NB) { st = lstart[b]; cnt = lcur[b] - st; g = gdst[b]; }
        for (unsigned k = ln8; k < cnt; k += 8) {
            payload[g + k] = recs_pl[st + k];
            key[g + k]     = recs_k[st + k];
        }
    }
}

// D (fused): one wg per 64-node bucket. Per CAPB-tile: key-histogram (keys
// cached in kbuf), wave-0 scan (64 bins, 1/lane), scatter payloads
// node-sorted into LDS, then 8 waves gather (8 nodes each): 8 lanes/edge,
// 4-deep guarded loads, fp16 x-gather (L2-resident), f32 register
// accumulate + shfl reduce. Fused self-loop+weight+clip epilogue.
__global__ __launch_bounds__(TB) void sort_gather_kernel(const float* __restrict__ x,
                                                         const __half* __restrict__ xh,
                                                         const float* __restrict__ weight,
                                                         const float* __restrict__ slw,
                                                         const unsigned* __restrict__ base,
                                                         const unsigned* __restrict__ totals,
                                                         const unsigned char* __restrict__ key,
                                                         const unsigned* __restrict__ payload,
                                                         float* __restrict__ out) {
    __shared__ unsigned buf[CAPB];                // 9.7 KB
    __shared__ unsigned char kbuf[CAPB];          // 2.4 KB
    __shared__ float accs[BNODES * DIM];          // 4 KB
    __shared__ unsigned ncnt[BNODES];
    __shared__ unsigned nstart[BNODES];
    __shared__ unsigned ncur[BNODES];
    int tid = threadIdx.x;
    int b = blockIdx.x;
    unsigned s0 = base[b];
    unsigned cnt = totals[b];
    int wv = tid >> 6, lane = tid & 63;
    int sub = lane >> 3, dc = lane & 7;
    const __half2* xh2 = (const __half2*)xh;
    const float QS = 1.0f / QSCALE;

    for (int i = tid; i < BNODES * DIM; i += TB) accs[i] = 0.0f;

    for (unsigned t0 = 0; t0 < cnt; t0 += CAPB) {
        unsigned tcnt = min((unsigned)CAPB, cnt - t0);
        unsigned g0 = s0 + t0;
        if (tid < BNODES) ncnt[tid] = 0;
        __syncthreads();
        for (unsigned i = tid; i < tcnt; i += TB) {
            unsigned char k = key[g0 + i];        // single global key read
            kbuf[i] = k;
            atomicAdd(&ncnt[k], 1u);
        }
        __syncthreads();
        if (tid < 64) {   // exclusive scan of 64 bins, 1 per lane (wave 0)
            unsigned c = ncnt[tid];
            unsigned xs = c;
#pragma unroll
            for (int off = 1; off < 64; off <<= 1) {
                unsigned y = __shfl_up(xs, off);
                if (tid >= off) xs += y;
            }
            nstart[tid] = xs - c;
            ncur[tid]   = xs - c;
        }
        __syncthreads();
        for (unsigned i = tid; i < tcnt; i += TB) {
            unsigned k = kbuf[i];                 // LDS instead of global re-read
            unsigned pos = atomicAdd(&ncur[k], 1u);
            buf[pos] = payload[g0 + i];
        }
        __syncthreads();
        // gather: wave wv handles nodes wv, wv+8, ... (8 nodes per wave)
        for (int nloc = wv; nloc < BNODES; nloc += (TB >> 6)) {
            unsigned lo = nstart[nloc];
            unsigned hi = lo + ncnt[nloc];
            float ax = 0.0f, ay = 0.0f;
            for (unsigned i = lo + (unsigned)sub; i < hi; i += 32) {
                unsigned r0 = buf[i];
                unsigned r1 = (i + 8  < hi) ? buf[i + 8]  : 0u;
                unsigned r2 = (i + 16 < hi) ? buf[i + 16] : 0u;
                unsigned r3 = (i + 24 < hi) ? buf[i + 24] : 0u;
                float2 f0 = __half22float2(xh2[(size_t)(r0 >> 15) * 8 + dc]);
                float2 f1 = __half22float2(xh2[(size_t)(r1 >> 15) * 8 + dc]);
                float2 f2 = __half22float2(xh2[(size_t)(r2 >> 15) * 8 + dc]);
                float2 f3 = __half22float2(xh2[(size_t)(r3 >> 15) * 8 + dc]);
                float p0 = (float)(r0 & 0x7FFFu) * QS;
                float p1 = (float)(r1 & 0x7FFFu) * QS;
                float p2 = (float)(r2 & 0x7FFFu) * QS;
                float p3 = (float)(r3 & 0x7FFFu) * QS;
                ax = fmaf(f0.x, p0, ax); ay = fmaf(f0.y, p0, ay);
                ax = fmaf(f1.x, p1, ax); ay = fmaf(f1.y, p1, ay);
                ax = fmaf(f2.x, p2, ax); ay = fmaf(f2.y, p2, ay);
                ax = fmaf(f3.x, p3, ax); ay = fmaf(f3.y, p3, ay);
            }
            ax += __shfl_xor(ax, 8);  ay += __shfl_xor(ay, 8);
            ax += __shfl_xor(ax, 16); ay += __shfl_xor(ay, 16);
            ax += __shfl_xor(ax, 32); ay += __shfl_xor(ay, 32);
            if (lane < 8) {   // owner-exclusive: one wave per node
                float2* a2 = (float2*)&accs[nloc * DIM + 2 * dc];
                float2 cur = *a2;
                cur.x += ax; cur.y += ay;
                *a2 = cur;
            }
        }
        __syncthreads();   // protect ncnt/buf before next tile
    }

    // epilogue: out = clip(x*(1+slw) + accs*weight, 0, 1)
    float sc = 1.0f + slw[0];
    for (int idx = tid; idx < BNODES * 8; idx += TB) {
        int nloc = idx >> 3, q = idx & 7;
        int n = b * BNODES + nloc;
        if (n >= N_NODES) continue;
        float2 a = ((float2*)accs)[nloc * 8 + q];
        float2 xv = ((const float2*)x)[(size_t)n * 8 + q];
        float2 wv2 = ((const float2*)weight)[q];
        float2 r;
        r.x = fminf(fmaxf(fmaf(xv.x, sc, a.x * wv2.x), 0.0f), 1.0f);
        r.y = fminf(fmaxf(fmaf(xv.y, sc, a.y * wv2.y), 0.0f), 1.0f);
        ((float2*)out)[(size_t)n * 8 + q] = r;
    }
}

// ---------------- fallback path (R1): direct float atomics ----------------

__global__ void diffusion_scatter_kernel(const float* __restrict__ x,
                                         const int* __restrict__ src,
                                         const int* __restrict__ dst,
                                         const float* __restrict__ probs,
                                         const float* __restrict__ weight,
                                         float* __restrict__ acc,
                                         int E) {
    int e = blockIdx.x * blockDim.x + threadIdx.x;
    if (e >= E) return;
    int s = src[e];
    int d = dst[e];
    float p = probs[e];
    const float4* xs = reinterpret_cast<const float4*>(x + (size_t)s * DIM);
    const float4* w4 = reinterpret_cast<const float4*>(weight);
    float* outp = acc + (size_t)d * DIM;
#pragma unroll
    for (int q = 0; q < 4; ++q) {
        float4 xv = xs[q];
        float4 wv = w4[q];
        atomicAdd(&outp[q * 4 + 0], xv.x * p * wv.x);
        atomicAdd(&outp[q * 4 + 1], xv.y * p * wv.y);
        atomicAdd(&outp[q * 4 + 2], xv.z * p * wv.z);
        atomicAdd(&outp[q * 4 + 3], xv.w * p * wv.w);
    }
}

__global__ void diffusion_finalize_kernel(const float* __restrict__ x,
                                          const float* __restrict__ slw,
                                          float* __restrict__ out,
                                          int n4) {
    int i = blockIdx.x * blockDim.x + threadIdx.x;
    if (i >= n4) return;
    float s = 1.0f + slw[0];
    float4 xv = reinterpret_cast<const float4*>(x)[i];
    float4 a = reinterpret_cast<float4*>(out)[i];
    float4 r;
    r.x = fminf(fmaxf(fmaf(xv.x, s, a.x), 0.0f), 1.0f);
    r.y = fminf(fmaxf(fmaf(xv.y, s, a.y), 0.0f), 1.0f);
    r.z = fminf(fmaxf(fmaf(xv.z, s, a.z), 0.0f), 1.0f);
    r.w = fminf(fmaxf(fmaf(xv.w, s, a.w), 0.0f), 1.0f);
    reinterpret_cast<float4*>(out)[i] = r;
}

extern "C" void kernel_launch(void* const* d_in, const int* in_sizes, int n_in,
                              void* d_out, int out_size, void* d_ws, size_t ws_size,
                              hipStream_t stream) {
    const float* x      = (const float*)d_in[0];
    const int*   eidx   = (const int*)d_in[1];   // [2, E]: row0=src, row1=dst
    const float* probs  = (const float*)d_in[2];
    const float* weight = (const float*)d_in[3];
    const float* slw    = (const float*)d_in[4];

    int E = in_sizes[2];
    float* out = (float*)d_out;

    int nwg = (E + CHUNK - 1) / CHUNK;   // 391 for E=3.2M

    // ws layout (16B-aligned segments):
    // H[nwg*NB] u32 | totals[NB] | base[NB] | xh[N*DIM] fp16 |
    // key[E] u8 | payload[E] u32
    size_t off = 0;
    auto alloc = [&](size_t bytes) { size_t o = off; off += (bytes + 15) & ~(size_t)15; return o; };
    size_t o_H       = alloc((size_t)nwg * NB * 4);
    size_t o_totals  = alloc((size_t)NB * 4);
    size_t o_base    = alloc((size_t)NB * 4);
    size_t o_xh      = alloc((size_t)N_NODES * DIM * 2);
    size_t o_key     = alloc((size_t)E);
    size_t o_payload = alloc((size_t)E * 4);
    size_t need = off;

    if (ws_size >= need && nwg <= TB) {
        char* ws = (char*)d_ws;
        unsigned* H           = (unsigned*)(ws + o_H);
        unsigned* totals      = (unsigned*)(ws + o_totals);
        unsigned* basep       = (unsigned*)(ws + o_base);
        __half*   xh          = (__half*)(ws + o_xh);
        unsigned char* key    = (unsigned char*)(ws + o_key);
        unsigned* payload     = (unsigned*)(ws + o_payload);

        int n8 = N_NODES * DIM / 8;
        hist_kernel<<<nwg, TB, 0, stream>>>(x, xh, n8, eidx + E, H, E);
        scan_wg_kernel<<<NB, TB, 0, stream>>>(H, totals, nwg);
        scan_bucket_kernel<<<1, 1024, 0, stream>>>(totals, basep);
        place_kernel<<<nwg, TB, 0, stream>>>(eidx, eidx + E, probs, H, totals, basep,
                                             key, payload, E, nwg);
        sort_gather_kernel<<<NB, TB, 0, stream>>>(x, xh, weight, slw, basep, totals,
                                                  key, payload, out);
    } else {
        const int T = 256;
        hipMemsetAsync(d_out, 0, (size_t)out_size * sizeof(float), stream);
        diffusion_scatter_kernel<<<(E + T - 1) / T, T, 0, stream>>>(
            x, eidx, eidx + E, probs, weight, out, E);
        int n4 = out_size / 4;
        diffusion_finalize_kernel<<<(n4 + T - 1) / T, T, 0, stream>>>(
            x, slw, out, n4);
    }
}

// Round 17
// 74.114 us; speedup vs baseline: 1.0804x; 1.0804x over previous
//
#include <hip/hip_runtime.h>
#include <hip/hip_fp16.h>

#define N_NODES 100000
#define DIM 16
#define BSHIFT 7
#define BNODES 128                                  // nodes per bucket
#define NB ((N_NODES + BNODES - 1) / BNODES)        // 782 buckets
#define TB 512
#define CHUNK 8192                                  // edges per place/hist wg
#define CAPB 4608                                   // sort_gather LDS tile capacity
#define QSCALE 32767.0f

// ---------------- two-level bucket sort + fused node-sort/gather ----------------

// A (+X): convert x->fp16 (grid-stride), then per-workgroup histogram of
// dst-buckets. Vectorized int4 dst reads.
__global__ __launch_bounds__(TB) void hist_kernel(const float* __restrict__ x,
                                                  __half* __restrict__ xh,
                                                  int n8,
                                                  const int* __restrict__ dst,
                                                  unsigned* __restrict__ H,
                                                  int E) {
    // convert: 8 floats -> 16B per thread
    int gid = blockIdx.x * TB + threadIdx.x;
    int gsz = gridDim.x * TB;
    for (int i = gid; i < n8; i += gsz) {
        float4 a = ((const float4*)x)[2 * i];
        float4 b = ((const float4*)x)[2 * i + 1];
        __half2 h0 = __floats2half2_rn(a.x, a.y);
        __half2 h1 = __floats2half2_rn(a.z, a.w);
        __half2 h2 = __floats2half2_rn(b.x, b.y);
        __half2 h3 = __floats2half2_rn(b.z, b.w);
        uint4 u;
        u.x = *reinterpret_cast<unsigned*>(&h0);
        u.y = *reinterpret_cast<unsigned*>(&h1);
        u.z = *reinterpret_cast<unsigned*>(&h2);
        u.w = *reinterpret_cast<unsigned*>(&h3);
        ((uint4*)xh)[i] = u;
    }

    __shared__ unsigned hist[NB];
    int tid = threadIdx.x;
    for (int i = tid; i < NB; i += TB) hist[i] = 0;
    __syncthreads();
    int e0 = blockIdx.x * CHUNK;
    int e1 = min(e0 + CHUNK, E);
    int nquad = ((E & 3) == 0) ? ((e1 - e0) >> 2) : 0;
    for (int qi = tid; qi < nquad; qi += TB) {
        int4 d4 = *(const int4*)(dst + e0 + qi * 4);
        atomicAdd(&hist[((unsigned)d4.x) >> BSHIFT], 1u);
        atomicAdd(&hist[((unsigned)d4.y) >> BSHIFT], 1u);
        atomicAdd(&hist[((unsigned)d4.z) >> BSHIFT], 1u);
        atomicAdd(&hist[((unsigned)d4.w) >> BSHIFT], 1u);
    }
    for (int e = e0 + nquad * 4 + tid; e < e1; e += TB)
        atomicAdd(&hist[((unsigned)dst[e]) >> BSHIFT], 1u);
    __syncthreads();
    unsigned* row = H + (size_t)blockIdx.x * NB;
    for (int i = tid; i < NB; i += TB) row[i] = hist[i];
}

// Block-wide exclusive scan (nthreads threads, multiple of 64, <=1024).
__device__ inline unsigned block_scan_excl(unsigned v, int tid, int nthreads,
                                           unsigned* warp_lds, unsigned* total_out) {
    unsigned x = v;
#pragma unroll
    for (int off = 1; off < 64; off <<= 1) {
        unsigned y = __shfl_up(x, off);
        if ((tid & 63) >= off) x += y;
    }
    int wid = tid >> 6;
    int nw = nthreads >> 6;
    if ((tid & 63) == 63) warp_lds[wid] = x;
    __syncthreads();
    if (tid < nw) {
        unsigned w = warp_lds[tid];
#pragma unroll
        for (int off = 1; off < 16; off <<= 1) {
            unsigned y = __shfl_up(w, off);
            if (tid >= off) w += y;
        }
        warp_lds[tid] = w;   // inclusive per-wave totals
    }
    __syncthreads();
    unsigned wbase = (wid > 0) ? warp_lds[wid - 1] : 0u;
    unsigned incl = x + wbase;
    if (total_out && tid == nthreads - 1) *total_out = incl;
    return incl - v;
}

// B1: for each bucket b, exclusive scan of H[wg][b] over wgs (in place) + total.
__global__ __launch_bounds__(TB) void scan_wg_kernel(unsigned* __restrict__ H,
                                                     unsigned* __restrict__ totals,
                                                     int nwg) {
    __shared__ unsigned warp_lds[16];
    int b = blockIdx.x;
    int tid = threadIdx.x;
    unsigned v = (tid < nwg) ? H[(size_t)tid * NB + b] : 0u;
    unsigned excl = block_scan_excl(v, tid, TB, warp_lds, &totals[b]);
    if (tid < nwg) H[(size_t)tid * NB + b] = excl;
}

// B2: exclusive scan of bucket totals -> bucket base offsets.
__global__ __launch_bounds__(1024) void scan_bucket_kernel(const unsigned* __restrict__ totals,
                                                           unsigned* __restrict__ base) {
    __shared__ unsigned warp_lds[16];
    int tid = threadIdx.x;
    unsigned v = (tid < NB) ? totals[tid] : 0u;
    unsigned excl = block_scan_excl(v, tid, 1024, warp_lds, nullptr);
    if (tid < NB) base[tid] = excl;
}

// C: LDS counting sort of the wg's chunk into (u8 dloc key, u32 src<<15|q15
// payload). Chunk counts from diffing adjacent scanned H rows. Vectorized
// 4-edge loads. Writeout: 16 lanes per bucket, 4 buckets per wave.
__global__ __launch_bounds__(TB) void place_kernel(const int* __restrict__ src,
                                                   const int* __restrict__ dst,
                                                   const float* __restrict__ probs,
                                                   const unsigned* __restrict__ O,
                                                   const unsigned* __restrict__ totals,
                                                   const unsigned* __restrict__ base,
                                                   unsigned char* __restrict__ key,
                                                   unsigned* __restrict__ payload,
                                                   int E, int nwg) {
    __shared__ unsigned recs_pl[CHUNK];           // 32 KB
    __shared__ unsigned char recs_k[CHUNK];       // 8 KB
    __shared__ unsigned lstart[NB];
    __shared__ unsigned lcur[NB];
    __shared__ unsigned gdst[NB];
    __shared__ unsigned warp_lds[16];
    int tid = threadIdx.x;
    int wg = blockIdx.x;
    int e0 = wg * CHUNK;
    int e1 = min(e0 + CHUNK, E);
    bool last = (wg == nwg - 1);

    const unsigned* row  = O + (size_t)wg * NB;
    const unsigned* rown = O + (size_t)(wg + 1) * NB;
    for (int i = tid; i < NB; i += TB) {
        unsigned h = row[i];
        unsigned hn = last ? totals[i] : rown[i];
        gdst[i] = base[i] + h;
        lcur[i] = hn - h;                  // count for this wg
    }
    __syncthreads();

    // scan 782 bins, 2 per thread
    int b0 = 2 * tid, b1 = 2 * tid + 1;
    unsigned c0 = (b0 < NB) ? lcur[b0] : 0u;
    unsigned c1 = (b1 < NB) ? lcur[b1] : 0u;
    unsigned excl = block_scan_excl(c0 + c1, tid, TB, warp_lds, nullptr);
    __syncthreads();
    if (b0 < NB) { lstart[b0] = excl;      lcur[b0] = excl; }
    if (b1 < NB) { lstart[b1] = excl + c0; lcur[b1] = excl + c0; }
    __syncthreads();

    // place records into LDS, bucket-sorted (vectorized 4-edge loads)
    int nquad = ((E & 3) == 0) ? ((e1 - e0) >> 2) : 0;
    for (int qi = tid; qi < nquad; qi += TB) {
        int e = e0 + qi * 4;
        int4   s4 = *(const int4*)(src + e);
        int4   d4 = *(const int4*)(dst + e);
        float4 p4 = *(const float4*)(probs + e);
#pragma unroll
        for (int u = 0; u < 4; ++u) {
            unsigned d = (unsigned)((&d4.x)[u]);
            unsigned s = (unsigned)((&s4.x)[u]);
            float p = (&p4.x)[u];
            unsigned bb = d >> BSHIFT;
            unsigned pos = atomicAdd(&lcur[bb], 1u);
            unsigned q = __float2uint_rn(p * QSCALE);
            recs_pl[pos] = (s << 15) | q;                 // src 17b | q 15b
            recs_k[pos] = (unsigned char)(d & (BNODES - 1));
        }
    }
    for (int e = e0 + nquad * 4 + tid; e < e1; e += TB) {
        unsigned d = (unsigned)dst[e];
        unsigned s = (unsigned)src[e];
        float p = probs[e];
        unsigned bb = d >> BSHIFT;
        unsigned pos = atomicAdd(&lcur[bb], 1u);
        unsigned q = __float2uint_rn(p * QSCALE);
        recs_pl[pos] = (s << 15) | q;
        recs_k[pos] = (unsigned char)(d & (BNODES - 1));
    }
    __syncthreads();

    // writeout: 16 lanes per bucket, 4 buckets per wave (runs avg ~10 recs)
    int wv = tid >> 6, ln = tid & 63;
    int bq = ln >> 4, ln16 = ln & 15;
    for (int bb = wv * 4; bb < NB; bb += (TB >> 6) * 4) {
        int b = bb + bq;
        unsigned st = 0, cnt = 0, g = 0;
        if (b < NB) { st = lstart[b]; cnt = lcur[b] - st; g = gdst[b]; }
        for (unsigned k = ln16; k < cnt; k += 16) {
            payload[g + k] = recs_pl[st + k];
            key[g + k]     = recs_k[st + k];
        }
    }
}

// D (fused): one wg per bucket. Per CAPB-tile: key-histogram (keys cached to
// LDS kbuf — read global keys once), wave-0 scan, scatter payloads node-sorted
// into LDS, then 8 waves gather: 8 lanes/edge, 4-deep guarded loads, fp16
// x-gather (L2-resident), f32 register accumulate + shfl reduce. Fused epilogue.
__global__ __launch_bounds__(TB) void sort_gather_kernel(const float* __restrict__ x,
                                                         const __half* __restrict__ xh,
                                                         const float* __restrict__ weight,
                                                         const float* __restrict__ slw,
                                                         const unsigned* __restrict__ base,
                                                         const unsigned* __restrict__ totals,
                                                         const unsigned char* __restrict__ key,
                                                         const unsigned* __restrict__ payload,
                                                         float* __restrict__ out) {
    __shared__ unsigned buf[CAPB];                // 18.4 KB
    __shared__ unsigned char kbuf[CAPB];          // 4.6 KB
    __shared__ float accs[BNODES * DIM];          // 8 KB
    __shared__ unsigned ncnt[BNODES];
    __shared__ unsigned nstart[BNODES];
    __shared__ unsigned ncur[BNODES];
    int tid = threadIdx.x;
    int b = blockIdx.x;
    unsigned s0 = base[b];
    unsigned cnt = totals[b];
    int wv = tid >> 6, lane = tid & 63;
    int sub = lane >> 3, dc = lane & 7;
    const __half2* xh2 = (const __half2*)xh;
    const float QS = 1.0f / QSCALE;

    for (int i = tid; i < BNODES * DIM; i += TB) accs[i] = 0.0f;

    for (unsigned t0 = 0; t0 < cnt; t0 += CAPB) {
        unsigned tcnt = min((unsigned)CAPB, cnt - t0);
        unsigned g0 = s0 + t0;
        if (tid < BNODES) ncnt[tid] = 0;
        __syncthreads();
        for (unsigned i = tid; i < tcnt; i += TB) {
            unsigned char k = key[g0 + i];        // single global key read
            kbuf[i] = k;
            atomicAdd(&ncnt[k], 1u);
        }
        __syncthreads();
        if (tid < 64) {   // exclusive scan of 128 bins, 2 per lane
            unsigned c0 = ncnt[2 * tid], c1 = ncnt[2 * tid + 1];
            unsigned v = c0 + c1;
            unsigned xs = v;
#pragma unroll
            for (int off = 1; off < 64; off <<= 1) {
                unsigned y = __shfl_up(xs, off);
                if (tid >= off) xs += y;
            }
            nstart[2 * tid]     = xs - v;  ncur[2 * tid]     = xs - v;
            nstart[2 * tid + 1] = xs - c1; ncur[2 * tid + 1] = xs - c1;
        }
        __syncthreads();
        for (unsigned i = tid; i < tcnt; i += TB) {
            unsigned k = kbuf[i];                 // LDS instead of global re-read
            unsigned pos = atomicAdd(&ncur[k], 1u);
            buf[pos] = payload[g0 + i];
        }
        __syncthreads();
        // gather: wave wv handles nodes wv, wv+8, ... (16 nodes per wave)
        for (int nloc = wv; nloc < BNODES; nloc += (TB >> 6)) {
            unsigned lo = nstart[nloc];
            unsigned hi = lo + ncnt[nloc];
            float ax = 0.0f, ay = 0.0f;
            for (unsigned i = lo + (unsigned)sub; i < hi; i += 32) {
                unsigned r0 = buf[i];
                unsigned r1 = (i + 8  < hi) ? buf[i + 8]  : 0u;
                unsigned r2 = (i + 16 < hi) ? buf[i + 16] : 0u;
                unsigned r3 = (i + 24 < hi) ? buf[i + 24] : 0u;
                float2 f0 = __half22float2(xh2[(size_t)(r0 >> 15) * 8 + dc]);
                float2 f1 = __half22float2(xh2[(size_t)(r1 >> 15) * 8 + dc]);
                float2 f2 = __half22float2(xh2[(size_t)(r2 >> 15) * 8 + dc]);
                float2 f3 = __half22float2(xh2[(size_t)(r3 >> 15) * 8 + dc]);
                float p0 = (float)(r0 & 0x7FFFu) * QS;
                float p1 = (float)(r1 & 0x7FFFu) * QS;
                float p2 = (float)(r2 & 0x7FFFu) * QS;
                float p3 = (float)(r3 & 0x7FFFu) * QS;
                ax = fmaf(f0.x, p0, ax); ay = fmaf(f0.y, p0, ay);
                ax = fmaf(f1.x, p1, ax); ay = fmaf(f1.y, p1, ay);
                ax = fmaf(f2.x, p2, ax); ay = fmaf(f2.y, p2, ay);
                ax = fmaf(f3.x, p3, ax); ay = fmaf(f3.y, p3, ay);
            }
            ax += __shfl_xor(ax, 8);  ay += __shfl_xor(ay, 8);
            ax += __shfl_xor(ax, 16); ay += __shfl_xor(ay, 16);
            ax += __shfl_xor(ax, 32); ay += __shfl_xor(ay, 32);
            if (lane < 8) {   // owner-exclusive: one wave per node
                float2* a2 = (float2*)&accs[nloc * DIM + 2 * dc];
                float2 cur = *a2;
                cur.x += ax; cur.y += ay;
                *a2 = cur;
            }
        }
        __syncthreads();   // protect ncnt/buf before next tile
    }

    // epilogue: out = clip(x*(1+slw) + accs*weight, 0, 1)
    float sc = 1.0f + slw[0];
    for (int idx = tid; idx < BNODES * 8; idx += TB) {
        int nloc = idx >> 3, q = idx & 7;
        int n = b * BNODES + nloc;
        if (n >= N_NODES) continue;
        float2 a = ((float2*)accs)[nloc * 8 + q];
        float2 xv = ((const float2*)x)[(size_t)n * 8 + q];
        float2 wv2 = ((const float2*)weight)[q];
        float2 r;
        r.x = fminf(fmaxf(fmaf(xv.x, sc, a.x * wv2.x), 0.0f), 1.0f);
        r.y = fminf(fmaxf(fmaf(xv.y, sc, a.y * wv2.y), 0.0f), 1.0f);
        ((float2*)out)[(size_t)n * 8 + q] = r;
    }
}

// ---------------- fallback path (R1): direct float atomics ----------------

__global__ void diffusion_scatter_kernel(const float* __restrict__ x,
                                         const int* __restrict__ src,
                                         const int* __restrict__ dst,
                                         const float* __restrict__ probs,
                                         const float* __restrict__ weight,
                                         float* __restrict__ acc,
                                         int E) {
    int e = blockIdx.x * blockDim.x + threadIdx.x;
    if (e >= E) return;
    int s = src[e];
    int d = dst[e];
    float p = probs[e];
    const float4* xs = reinterpret_cast<const float4*>(x + (size_t)s * DIM);
    const float4* w4 = reinterpret_cast<const float4*>(weight);
    float* outp = acc + (size_t)d * DIM;
#pragma unroll
    for (int q = 0; q < 4; ++q) {
        float4 xv = xs[q];
        float4 wv = w4[q];
        atomicAdd(&outp[q * 4 + 0], xv.x * p * wv.x);
        atomicAdd(&outp[q * 4 + 1], xv.y * p * wv.y);
        atomicAdd(&outp[q * 4 + 2], xv.z * p * wv.z);
        atomicAdd(&outp[q * 4 + 3], xv.w * p * wv.w);
    }
}

__global__ void diffusion_finalize_kernel(const float* __restrict__ x,
                                          const float* __restrict__ slw,
                                          float* __restrict__ out,
                                          int n4) {
    int i = blockIdx.x * blockDim.x + threadIdx.x;
    if (i >= n4) return;
    float s = 1.0f + slw[0];
    float4 xv = reinterpret_cast<const float4*>(x)[i];
    float4 a = reinterpret_cast<float4*>(out)[i];
    float4 r;
    r.x = fminf(fmaxf(fmaf(xv.x, s, a.x), 0.0f), 1.0f);
    r.y = fminf(fmaxf(fmaf(xv.y, s, a.y), 0.0f), 1.0f);
    r.z = fminf(fmaxf(fmaf(xv.z, s, a.z), 0.0f), 1.0f);
    r.w = fminf(fmaxf(fmaf(xv.w, s, a.w), 0.0f), 1.0f);
    reinterpret_cast<float4*>(out)[i] = r;
}

extern "C" void kernel_launch(void* const* d_in, const int* in_sizes, int n_in,
                              void* d_out, int out_size, void* d_ws, size_t ws_size,
                              hipStream_t stream) {
    const float* x      = (const float*)d_in[0];
    const int*   eidx   = (const int*)d_in[1];   // [2, E]: row0=src, row1=dst
    const float* probs  = (const float*)d_in[2];
    const float* weight = (const float*)d_in[3];
    const float* slw    = (const float*)d_in[4];

    int E = in_sizes[2];
    float* out = (float*)d_out;

    int nwg = (E + CHUNK - 1) / CHUNK;   // 391 for E=3.2M

    // ws layout (16B-aligned segments):
    // H[nwg*NB] u32 | totals[NB] | base[NB] | xh[N*DIM] fp16 |
    // key[E] u8 | payload[E] u32
    size_t off = 0;
    auto alloc = [&](size_t bytes) { size_t o = off; off += (bytes + 15) & ~(size_t)15; return o; };
    size_t o_H       = alloc((size_t)nwg * NB * 4);
    size_t o_totals  = alloc((size_t)NB * 4);
    size_t o_base    = alloc((size_t)NB * 4);
    size_t o_xh      = alloc((size_t)N_NODES * DIM * 2);
    size_t o_key     = alloc((size_t)E);
    size_t o_payload = alloc((size_t)E * 4);
    size_t need = off;

    if (ws_size >= need && nwg <= TB) {
        char* ws = (char*)d_ws;
        unsigned* H           = (unsigned*)(ws + o_H);
        unsigned* totals      = (unsigned*)(ws + o_totals);
        unsigned* basep       = (unsigned*)(ws + o_base);
        __half*   xh          = (__half*)(ws + o_xh);
        unsigned char* key    = (unsigned char*)(ws + o_key);
        unsigned* payload     = (unsigned*)(ws + o_payload);

        int n8 = N_NODES * DIM / 8;
        hist_kernel<<<nwg, TB, 0, stream>>>(x, xh, n8, eidx + E, H, E);
        scan_wg_kernel<<<NB, TB, 0, stream>>>(H, totals, nwg);
        scan_bucket_kernel<<<1, 1024, 0, stream>>>(totals, basep);
        place_kernel<<<nwg, TB, 0, stream>>>(eidx, eidx + E, probs, H, totals, basep,
                                             key, payload, E, nwg);
        sort_gather_kernel<<<NB, TB, 0, stream>>>(x, xh, weight, slw, basep, totals,
                                                  key, payload, out);
    } else {
        const int T = 256;
        hipMemsetAsync(d_out, 0, (size_t)out_size * sizeof(float), stream);
        diffusion_scatter_kernel<<<(E + T - 1) / T, T, 0, stream>>>(
            x, eidx, eidx + E, probs, weight, out, E);
        int n4 = out_size / 4;
        diffusion_finalize_kernel<<<(n4 + T - 1) / T, T, 0, stream>>>(
            x, slw, out, n4);
    }
}